// Round 13
// baseline (439.705 us; speedup 1.0000x reference)
//
#include <hip/hip_runtime.h>
#include <math.h>

#define D 128
#define NF 10
#define N_IP 20000
#define N_CONN 100000
#define NE 200000
#define T_ROUNDS 3

typedef unsigned short u16;
using bf16x8 = __attribute__((ext_vector_type(8))) short;
using floatx4 = __attribute__((ext_vector_type(4))) float;

__device__ inline u16 f2bf(float f) {
  union { float f; unsigned u; } v; v.f = f;
  unsigned u = v.u;
  return (u16)((u + 0x7fffu + ((u >> 16) & 1u)) >> 16);  // RNE
}
__device__ inline float bf2f(u16 h) {
  union { unsigned u; float f; } v; v.u = ((unsigned)h) << 16; return v.f;
}
// HW packed f32->bf16 (RNE, identical to f2bf) — 1 inst per 2 values.
__device__ __forceinline__ unsigned cvtpk(float lo, float hi) {
  unsigned r;
  asm("v_cvt_pk_bf16_f32 %0, %1, %2" : "=v"(r) : "v"(lo), "v"(hi));
  return r;
}

__device__ inline float fsigmoid(float s) { return 1.f / (1.f + __expf(-s)); }
__device__ inline float ftanh(float a) {
  a = fminf(fmaxf(a, -15.f), 15.f);
  float e = __expf(2.f * a);
  return (e - 1.f) / (e + 1.f);
}

// async global->LDS, 16B per lane. LDS dest is wave-linear (base + lane*16B);
// swizzled layouts are realized by pre-swizzling the per-lane GLOBAL address.
__device__ __forceinline__ void gld16(const u16* g, u16* l) {
  __builtin_amdgcn_global_load_lds(
      (const __attribute__((address_space(1))) unsigned int*)g,
      (__attribute__((address_space(3))) unsigned int*)l, 16, 0, 0);
}

// ---------------- merged setup: weights + colsum + edge count + P2 init ----------------
// cnt/gctr pre-zeroed via hipMemsetAsync. Weight prep iterates in SOURCE-linear order
// (reads fully coalesced; 2B writes strided — fire-and-forget). P2 part: one block =
// 16 conn nodes, feat rows LDS-staged via aligned float2 loads.
// Grid: N_CONN/16 = 6250 blocks x 256.
__global__ void k_setup(const float* __restrict__ feat,
                        const int* __restrict__ d1, const int* __restrict__ d2,
                        int* __restrict__ c1, int* __restrict__ c2,
                        u16* __restrict__ P2,
                        const float* __restrict__ gik, const float* __restrict__ gir,
                        const float* __restrict__ gck, const float* __restrict__ gcr,
                        const float* __restrict__ Wm1, const float* __restrict__ Wm2,
                        const float* __restrict__ Wr1, const float* __restrict__ Wr2,
                        u16* __restrict__ gikb, u16* __restrict__ girb,
                        u16* __restrict__ gckb, u16* __restrict__ gcrb,
                        u16* __restrict__ wm1b, u16* __restrict__ wm2b,
                        u16* __restrict__ wm1t, u16* __restrict__ wm2t,
                        u16* __restrict__ wr1b, u16* __restrict__ wr2b,
                        float* __restrict__ csum) {
  __shared__ float featLs[160];  // 16 nodes x 10 features
  const int b = blockIdx.x, t = threadIdx.x;
  const int i = b * 256 + t;
  // stage this block's 16 feat rows (160 contiguous floats, 8B-aligned float2 loads)
  if (t < 80) {
    float2 v = *(const float2*)(feat + (size_t)b * 160 + 2 * t);
    featLs[2 * t] = v.x;
    featLs[2 * t + 1] = v.y;
  }
  // edge degree counting (cnt pre-zeroed by memset)
  if (i < NE) {
    atomicAdd(&c1[d1[i]], 1);
    atomicAdd(&c2[d2[i]], 1);
  }
  // weight prep — SOURCE-linear indexing: consecutive threads read consecutive floats.
  if (i < 196608) {  // 4 GRU mats [128][384] -> [col][k] bf16
    int m = i / 49152, r = i % 49152;  // r == k*384 + col (linear read)
    const float* W = (m == 0) ? gik : (m == 1) ? gir : (m == 2) ? gck : gcr;
    u16* Wb = (m == 0) ? gikb : (m == 1) ? girb : (m == 2) ? gckb : gcrb;
    int k = r / 384, col = r % 384;
    Wb[(size_t)col * 128 + k] = f2bf(W[r]);
  } else if (i < 278528) {  // 5 x 128x128 blocks
    int j = i - 196608;
    int m = j / 16384, r = j % 16384;  // r == k*128 + col (linear within block)
    const float* W; u16* Wb; int k0;
    if (m == 0) { W = Wm1; Wb = wm1b; k0 = 128; }
    else if (m == 1) { W = Wm2; Wb = wm2b; k0 = 128; }
    else if (m == 2) { W = Wm1; Wb = wm1t; k0 = 0; }
    else if (m == 3) { W = Wm2; Wb = wm2t; k0 = 0; }
    else { W = Wr1; Wb = wr1b; k0 = 0; }
    int k = r / 128, col = r % 128;
    Wb[(size_t)col * 128 + k] = f2bf(W[(size_t)k0 * 128 + r]);
  } else if (i < 286720) {  // Wr2 [128][64] -> [col][k]
    int r = i - 278528;  // r == k*64 + col
    int k = r / 64, col = r % 64;
    wr2b[(size_t)col * 128 + k] = f2bf(Wr2[r]);
  } else if (i < 286848) {  // colsum of Wm1_top (ip_state0 == 1)
    int c = i - 286720;
    float s = 0.f;
    for (int k = 0; k < 128; k++) s += Wm1[k * 128 + c];
    csum[c] = s;
  }
  __syncthreads();
  // P2_0 = feat @ Wm2[0:NF,:] for node r = b*16 + (t>>4), col group g = t&15.
  {
    int nl = t >> 4, g = t & 15;
    int r = b * 16 + nl;  // 6250*16 == N_CONN exactly
    float acc[8] = {0.f, 0.f, 0.f, 0.f, 0.f, 0.f, 0.f, 0.f};
#pragma unroll
    for (int k = 0; k < NF; k++) {
      float f = featLs[nl * 10 + k];
      const float* wrow = Wm2 + (size_t)k * 128 + g * 8;
#pragma unroll
      for (int c = 0; c < 8; c++) acc[c] += f * wrow[c];
    }
    u16 v[8];
#pragma unroll
    for (int c = 0; c < 8; c++) v[c] = f2bf(acc[c]);
    *(uint4*)(P2 + (size_t)r * 128 + g * 8) = *(const uint4*)v;
  }
}

// ---------------- single-kernel CSR offset allocation ----------------
__global__ void k_alloc(const int* __restrict__ cnt1, int* __restrict__ off1,
                        int* __restrict__ cur1, int n1, int nb1,
                        const int* __restrict__ cnt2, int* __restrict__ off2,
                        int* __restrict__ cur2, int n2, int* __restrict__ gctr) {
  const int* cnt; int* off; int* cur; int n, b; int* g;
  if ((int)blockIdx.x < nb1) {
    cnt = cnt1; off = off1; cur = cur1; n = n1; b = blockIdx.x; g = gctr;
  } else {
    cnt = cnt2; off = off2; cur = cur2; n = n2; b = blockIdx.x - nb1; g = gctr + 1;
  }
  int t = threadIdx.x;
  int base = b * 1024 + t * 4;
  int vals[4]; int s = 0;
#pragma unroll
  for (int i = 0; i < 4; i++) {
    int j = base + i;
    vals[i] = (j < n) ? cnt[j] : 0;
    s += vals[i];
  }
  int lane = t & 63, wv = t >> 6;
  int x = s;
  for (int d = 1; d < 64; d <<= 1) { int y = __shfl_up(x, d, 64); if (lane >= d) x += y; }
  __shared__ int wsum[4];
  __shared__ int gbase;
  if (lane == 63) wsum[wv] = x;
  __syncthreads();
  int add = 0;
  for (int i = 0; i < wv; i++) add += wsum[i];
  if (t == 0) gbase = atomicAdd(g, wsum[0] + wsum[1] + wsum[2] + wsum[3]);
  __syncthreads();
  int run = gbase + add + x - s;
#pragma unroll
  for (int i = 0; i < 4; i++) {
    int j = base + i;
    if (j < n) { off[j] = run; cur[j] = run; }
    run += vals[i];
  }
}

__global__ void k_scatter(const int* __restrict__ s1, const int* __restrict__ d1,
                          const int* __restrict__ s2, const int* __restrict__ d2,
                          int* __restrict__ cur1, int* __restrict__ cur2,
                          int* __restrict__ o1, int* __restrict__ o2) {
  int e = blockIdx.x * blockDim.x + threadIdx.x;
  if (e >= NE) return;
  int p1 = atomicAdd(&cur1[d1[e]], 1);
  o1[p1] = s1[e];
  int p2 = atomicAdd(&cur2[d2[e]], 1);
  o2[p2] = s2[e];
}

// ---------------- fused message+GRU+{nextP | readout}: 512 threads, 128 rows/block ----------------
// an0 (round 0): states synthesized analytically. New: first-batch srcs indices are
// PREFETCHED right after off/cnt (srcs arrays +8 padded) so the gather's first P loads
// issue without a serial srcs round-trip. Values identical (rem>j ? srcs[o+j] : srcs[o]).
__global__ __launch_bounds__(512, 4) void k_msggru(
    u16* __restrict__ st1, const u16* __restrict__ wq1, const float* __restrict__ qb1,
    const u16* __restrict__ P1g, const int* __restrict__ srcs1g,
    const int* __restrict__ off1g, const int* __restrict__ cnt1g,
    const u16* __restrict__ wx1, const u16* __restrict__ wh1, const float* __restrict__ gb1,
    const u16* __restrict__ wp1, u16* __restrict__ Pn1, int r1, int tiles1,
    u16* __restrict__ st2, const u16* __restrict__ wq2, const float* __restrict__ qb2,
    const u16* __restrict__ P2g, const int* __restrict__ srcs2g,
    const int* __restrict__ off2g, const int* __restrict__ cnt2g,
    const u16* __restrict__ wx2, const u16* __restrict__ wh2, const float* __restrict__ gb2,
    const u16* __restrict__ wp2, u16* __restrict__ Pn2, int r2, int doP,
    const u16* __restrict__ w1r, const float* __restrict__ b1r,
    const u16* __restrict__ w2r, const float* __restrict__ b2r,
    const float* __restrict__ W3r, const float* __restrict__ b3r,
    float* __restrict__ outp, int doRd,
    const float* __restrict__ featp, const float* __restrict__ csumP, int an0) {
  __shared__ __align__(16) char smem[65536];
  u16* Wls = (u16*)smem;                   // staged weight matrix (up to 32KB)
  u16* Qb = (u16*)smem;                    // 128x128 bf16 (32KB); Xb overlays swizzled
  u16* bufA = (u16*)smem;                  // GRU x-gates chunk (12KB)
  u16* bufB = (u16*)(smem + 12288);        // GRU h-gates chunk (12KB)
  u16* Hls = (u16*)(smem + 32768);         // 128x128 bf16 swizzled (32KB)
  u16* H; const u16* Wqb; const float* qbias; const u16* P;
  const int* srcs; const int* off; const int* cnt;
  const u16* Wxb; const u16* Whb; const float* gbias;
  const u16* Wpt; u16* Pn; int rows, bm;
  const bool side2 = (int)blockIdx.x >= tiles1;
  if (!side2) {
    H = st1; Wqb = wq1; qbias = qb1; P = P1g; srcs = srcs1g; off = off1g; cnt = cnt1g;
    Wxb = wx1; Whb = wh1; gbias = gb1; Wpt = wp1; Pn = Pn1; rows = r1; bm = blockIdx.x * 128;
  } else {
    H = st2; Wqb = wq2; qbias = qb2; P = P2g; srcs = srcs2g; off = off2g; cnt = cnt2g;
    Wxb = wx2; Whb = wh2; gbias = gb2; Wpt = wp2; Pn = Pn2; rows = r2;
    bm = (blockIdx.x - tiles1) * 128;
  }
  const int tid = threadIdx.x, wv = tid >> 6, lane = tid & 63;
  const int lrow = lane & 15, quad = lane >> 4;
  const bool anIp = an0 && !side2;    // analytic all-ones state
  const bool anConn = an0 && side2;   // analytic [feat|0] state + closed-form gather
  // --- phase A: issue FULL Wq (2048 chunks) + H staging ---
#pragma unroll
  for (int j = 0; j < 4; j++) {
    int c = j * 512 + tid;
    int row = c >> 4, sl = c & 15;
    gld16(Wqb + (size_t)row * 128 + ((sl ^ (row & 15)) * 8), Wls + (size_t)c * 8);
  }
  if (!an0) {
#pragma unroll
    for (int i = 0; i < 4; i++) {
      int c = i * 512 + tid;
      int row = c >> 4, sl = c & 15;
      gld16(H + (size_t)(bm + row) * 128 + ((sl ^ (row & 15)) * 8), Hls + (size_t)c * 8);
    }
  } else if (anConn) {
    // synthesize conn_state0 = [feat|0] directly into Hls (swizzled), same f2bf values
#pragma unroll
    for (int i = 0; i < 4; i++) {
      int c = i * 512 + tid;
      int row = c >> 4, sl = c & 15;
      int grow = bm + row;
      u16 v[8];
#pragma unroll
      for (int k = 0; k < 8; k++) {
        int col = sl * 8 + k;
        v[k] = (grow < rows && col < NF) ? f2bf(featp[(size_t)grow * NF + col]) : (u16)0;
      }
      *(uint4*)(Hls + (size_t)row * 128 + ((sl ^ (row & 15)) * 8)) = *(const uint4*)v;
    }
  }
  // off/cnt for this thread's 4 gather tasks -> registers, then PREFETCH first-batch
  // srcs indices (srcs padded +8 -> unconditional 4-wide reads are in-bounds).
  int oArr[4], nArr[4];
  int sPre[4][4];
#pragma unroll
  for (int it = 0; it < 4; it++) {
    int nl = (it * 512 + tid) >> 4;
    int node = bm + nl;
    oArr[it] = (node < rows) ? off[node] : 0;
    nArr[it] = (node < rows) ? cnt[node] : 0;
  }
#pragma unroll
  for (int it = 0; it < 4; it++) {
#pragma unroll
    for (int j = 0; j < 4; j++) sPre[it][j] = srcs[oArr[it] + j];
  }
  __syncthreads();  // Wq + Hls ready
  // state A-frags (serve Q-GEMM and GRU h-GEMM); wave wv owns rows [wv*16, wv*16+16)
  bf16x8 ah[4];
  if (anIp) {
    bf16x8 ones;
#pragma unroll
    for (int k = 0; k < 8; k++) ones[k] = (short)0x3F80;  // bf16(1.0)
#pragma unroll
    for (int ks = 0; ks < 4; ks++) ah[ks] = ones;
  } else {
#pragma unroll
    for (int ks = 0; ks < 4; ks++)
      ah[ks] = *(const bf16x8*)(Hls + (size_t)(wv * 16 + lrow) * 128 + (((ks * 4 + quad) ^ lrow) * 8));
  }
  // --- Q-GEMM: full 128 cols in one pass ---
  floatx4 acc[8];
#pragma unroll
  for (int ct = 0; ct < 8; ct++) acc[ct] = {0.f, 0.f, 0.f, 0.f};
#pragma unroll
  for (int ks = 0; ks < 4; ks++) {
#pragma unroll
    for (int ct = 0; ct < 8; ct++) {
      bf16x8 b = *(const bf16x8*)(Wls + (size_t)(ct * 16 + lrow) * 128 + (((4 * ks + quad) ^ lrow) * 8));
      acc[ct] = __builtin_amdgcn_mfma_f32_16x16x32_bf16(ah[ks], b, acc[ct], 0, 0, 0);
    }
  }
  __syncthreads();  // Wq reads done; region0 becomes Qb
  // --- write Q (+bias) as bf16 via cvt_pk, plain [row][col] ---
  {
    const int lr = wv * 16 + quad * 4;
#pragma unroll
    for (int ct = 0; ct < 8; ct++) {
      int col = ct * 16 + lrow;
      float bv = qbias[col];
      unsigned p01 = cvtpk(acc[ct][0] + bv, acc[ct][1] + bv);
      unsigned p23 = cvtpk(acc[ct][2] + bv, acc[ct][3] + bv);
      Qb[(size_t)(lr + 0) * 128 + col] = (u16)p01;
      Qb[(size_t)(lr + 1) * 128 + col] = (u16)(p01 >> 16);
      Qb[(size_t)(lr + 2) * 128 + col] = (u16)p23;
      Qb[(size_t)(lr + 3) * 128 + col] = (u16)(p23 >> 16);
    }
  }
  __syncthreads();
  // --- gather-mean: X[node] = mean_e relu(P[src_e] + Q[node]) -> Xb (=Qb, swizzled)
#pragma unroll
  for (int it = 0; it < 4; it++) {
    int task = it * 512 + tid;
    int nl = task >> 4, g = task & 15;
    int node = bm + nl;
    if (node >= rows) continue;
    int c8 = g << 3;
    float q[8];
    {
      uint4 qv = *(const uint4*)(Qb + (size_t)nl * 128 + c8);
      unsigned qq[4] = {qv.x, qv.y, qv.z, qv.w};
#pragma unroll
      for (int k = 0; k < 4; k++) {
        q[2 * k] = __uint_as_float(qq[k] << 16);
        q[2 * k + 1] = __uint_as_float(qq[k] & 0xffff0000u);
      }
    }
    float acg[8] = {0.f, 0.f, 0.f, 0.f, 0.f, 0.f, 0.f, 0.f};
    int n = nArr[it];
    if (anConn) {
      // P1 round-0 rows are ALL IDENTICAL (= f2bf(csum)); mean over n copies ==
      // t added n times then * 1/max(n,1) — exact FP op order of the gather loop.
      float t[8];
#pragma unroll
      for (int k = 0; k < 8; k++)
        t[k] = fmaxf(bf2f(f2bf(csumP[c8 + k])) + q[k], 0.f);
      for (int i = 0; i < n; i++) {
#pragma unroll
        for (int k = 0; k < 8; k++) acg[k] += t[k];
      }
    } else {
      int o = oArr[it];
      for (int i = 0; i < n; i += 4) {
        int rem = n - i;
        int s0, s1, s2, s3;
        if (i == 0) {  // prefetched (issued before Q-GEMM); identical clamp semantics
          s0 = sPre[it][0];
          s1 = (rem > 1) ? sPre[it][1] : sPre[it][0];
          s2 = (rem > 2) ? sPre[it][2] : sPre[it][0];
          s3 = (rem > 3) ? sPre[it][3] : sPre[it][0];
        } else {
          s0 = srcs[o + i];
          s1 = srcs[o + i + (rem > 1 ? 1 : 0)];
          s2 = srcs[o + i + (rem > 2 ? 2 : 0)];
          s3 = srcs[o + i + (rem > 3 ? 3 : 0)];
        }
        uint4 v0 = *(const uint4*)(P + (size_t)s0 * 128 + c8);
        uint4 v1 = *(const uint4*)(P + (size_t)s1 * 128 + c8);
        uint4 v2 = *(const uint4*)(P + (size_t)s2 * 128 + c8);
        uint4 v3 = *(const uint4*)(P + (size_t)s3 * 128 + c8);
        unsigned w[16] = {v0.x, v0.y, v0.z, v0.w, v1.x, v1.y, v1.z, v1.w,
                          v2.x, v2.y, v2.z, v2.w, v3.x, v3.y, v3.z, v3.w};
#pragma unroll
        for (int e = 0; e < 4; e++) {
          bool val = (e == 0) || (rem > e);
#pragma unroll
          for (int k = 0; k < 4; k++) {
            unsigned ww = w[e * 4 + k];
            float lo = __uint_as_float(ww << 16);
            float hi = __uint_as_float(ww & 0xffff0000u);
            float t0 = fmaxf(lo + q[2 * k], 0.f);
            float t1 = fmaxf(hi + q[2 * k + 1], 0.f);
            if (val) { acg[2 * k] += t0; acg[2 * k + 1] += t1; }
          }
        }
      }
    }
    float inv = 1.f / fmaxf((float)n, 1.f);
    uint4 ov;
    ov.x = cvtpk(acg[0] * inv, acg[1] * inv);
    ov.y = cvtpk(acg[2] * inv, acg[3] * inv);
    ov.z = cvtpk(acg[4] * inv, acg[5] * inv);
    ov.w = cvtpk(acg[6] * inv, acg[7] * inv);
    *(uint4*)(Qb + (size_t)nl * 128 + ((g ^ (nl & 15)) * 8)) = ov;  // Xb overlay
  }
  __syncthreads();
  // --- x A-frags from Xb (= Qb region, swizzled) ---
  bf16x8 ax[4];
#pragma unroll
  for (int ks = 0; ks < 4; ks++)
    ax[ks] = *(const bf16x8*)(Qb + (size_t)(wv * 16 + lrow) * 128 + (((ks * 4 + quad) ^ lrow) * 8));
  const int lr0 = wv * 16 + quad * 4;
  __syncthreads();  // all Xb/Qb reads done; region0 free for GRU staging
  // --- GRU chunk loop: x/h ping-pong via global_load_lds (768 16B-chunks per buf) ---
#pragma unroll
  for (int j = 0; j < 2; j++) {  // stage x(0) -> bufA
    int c = j * 512 + tid;
    if (c < 768) {
      int gate = c >> 8, colw = (c >> 4) & 15, sl = c & 15;
      gld16(Wxb + (size_t)(gate * 128 + 0 * 16 + colw) * 128 + ((sl ^ colw) * 8),
            bufA + (size_t)c * 8);
    }
  }
  for (int ch = 0; ch < 8; ch++) {
    __syncthreads();  // bufA=x(ch) ready; prev bufB reads done
#pragma unroll
    for (int j = 0; j < 2; j++) {  // stage h(ch) -> bufB (overlaps MFMA-x)
      int c = j * 512 + tid;
      if (c < 768) {
        int gate = c >> 8, colw = (c >> 4) & 15, sl = c & 15;
        gld16(Whb + (size_t)(gate * 128 + ch * 16 + colw) * 128 + ((sl ^ colw) * 8),
              bufB + (size_t)c * 8);
      }
    }
    floatx4 gacc[3][2];
#pragma unroll
    for (int g = 0; g < 3; g++) {
      gacc[g][0] = {0.f, 0.f, 0.f, 0.f};
      gacc[g][1] = {0.f, 0.f, 0.f, 0.f};
    }
#pragma unroll
    for (int ks = 0; ks < 4; ks++) {
      int posu = ((4 * ks + quad) ^ lrow) * 8;
#pragma unroll
      for (int g = 0; g < 3; g++) {
        bf16x8 bx = *(const bf16x8*)(bufA + (size_t)(g * 16 + lrow) * 128 + posu);
        gacc[g][0] = __builtin_amdgcn_mfma_f32_16x16x32_bf16(ax[ks], bx, gacc[g][0], 0, 0, 0);
      }
    }
    __syncthreads();  // bufB=h(ch) ready; bufA reads done
    if (ch < 7) {
#pragma unroll
      for (int j = 0; j < 2; j++) {  // stage x(ch+1) -> bufA (overlaps MFMA-h + epilogue)
        int c = j * 512 + tid;
        if (c < 768) {
          int gate = c >> 8, colw = (c >> 4) & 15, sl = c & 15;
          gld16(Wxb + (size_t)(gate * 128 + (ch + 1) * 16 + colw) * 128 + ((sl ^ colw) * 8),
                bufA + (size_t)c * 8);
        }
      }
    }
#pragma unroll
    for (int ks = 0; ks < 4; ks++) {
      int posu = ((4 * ks + quad) ^ lrow) * 8;
#pragma unroll
      for (int g = 0; g < 3; g++) {
        bf16x8 bh = *(const bf16x8*)(bufB + (size_t)(g * 16 + lrow) * 128 + posu);
        gacc[g][1] = __builtin_amdgcn_mfma_f32_16x16x32_bf16(ah[ks], bh, gacc[g][1], 0, 0, 0);
      }
    }
    int hcol = ch * 16 + lrow;
    float bxz = gbias[hcol];
    float bxr = gbias[128 + hcol];
    float bxh = gbias[256 + hcol];
    float bhz = gbias[384 + hcol];
    float bhr = gbias[384 + 128 + hcol];
    float bhh = gbias[384 + 256 + hcol];
    int ggr = 2 * ch + (lrow >> 3);
    int gel = lrow & 7;
    float hn[4];
#pragma unroll
    for (int reg = 0; reg < 4; reg++) {
      int lr = lr0 + reg;
      float xz = gacc[0][0][reg] + bxz;
      float xr = gacc[1][0][reg] + bxr;
      float xh = gacc[2][0][reg] + bxh;
      float hz = gacc[0][1][reg] + bhz;
      float hr = gacc[1][1][reg] + bhr;
      float hh = gacc[2][1][reg] + bhh;
      float z = fsigmoid(xz + hz);
      float rr = fsigmoid(xr + hr);
      float hc = ftanh(xh + rr * hh);
      float hold;
      if (anIp) {
        hold = 1.0f;  // == bf2f(0x3F80)
      } else {
        const u16* hp = Hls + (size_t)lr * 128 + ((ggr ^ (lr & 15)) * 8) + gel;
        hold = bf2f(*hp);
      }
      hn[reg] = z * hold + (1.f - z) * hc;
    }
    unsigned q01 = cvtpk(hn[0], hn[1]);
    unsigned q23 = cvtpk(hn[2], hn[3]);
#define HPTR(R) (Hls + (size_t)(lr0 + (R)) * 128 + ((ggr ^ ((lr0 + (R)) & 15)) * 8) + gel)
    *HPTR(0) = (u16)q01;
    *HPTR(1) = (u16)(q01 >> 16);
    *HPTR(2) = (u16)q23;
    *HPTR(3) = (u16)(q23 >> 16);
#undef HPTR
  }
  __syncthreads();  // Hls updated block-wide; bufA/bufB reads done
  // --- coalesced state write-out (2048 chunks); DEAD in the readout round ---
  if (!doRd) {
#pragma unroll
    for (int i = 0; i < 4; i++) {
      int c = i * 512 + tid;
      int row = c >> 4, g = c & 15;
      int grow = bm + row;
      if (grow < rows)
        *(uint4*)(H + (size_t)grow * 128 + g * 8) =
            *(const uint4*)(Hls + (size_t)row * 128 + ((g ^ (row & 15)) * 8));
    }
  }
  if (doP) {
    // --- fused next-round P: Pn = h_new @ Wm_top, Wp staged FULL in one phase ---
    bf16x8 ah2[4];
#pragma unroll
    for (int ks = 0; ks < 4; ks++)
      ah2[ks] = *(const bf16x8*)(Hls + (size_t)(wv * 16 + lrow) * 128 + (((ks * 4 + quad) ^ lrow) * 8));
#pragma unroll
    for (int j = 0; j < 4; j++) {  // full 32KB Wp into region0 (bufA/B dead)
      int c = j * 512 + tid;
      int row = c >> 4, sl = c & 15;
      gld16(Wpt + (size_t)row * 128 + ((sl ^ (row & 15)) * 8), Wls + (size_t)c * 8);
    }
    __syncthreads();  // Wp ready; all Hls reads (writeout + ah2) done block-wide
#pragma unroll
    for (int ct = 0; ct < 8; ct++) acc[ct] = {0.f, 0.f, 0.f, 0.f};
#pragma unroll
    for (int ks = 0; ks < 4; ks++) {
#pragma unroll
      for (int ct = 0; ct < 8; ct++) {
        bf16x8 b = *(const bf16x8*)(Wls + (size_t)(ct * 16 + lrow) * 128 + (((4 * ks + quad) ^ lrow) * 8));
        acc[ct] = __builtin_amdgcn_mfma_f32_16x16x32_bf16(ah2[ks], b, acc[ct], 0, 0, 0);
      }
    }
    // Cls bounce over dead Hls
    u16* Cls = Hls;
    {
      const int lr = wv * 16 + quad * 4;
#pragma unroll
      for (int ct = 0; ct < 8; ct++) {
        int col = ct * 16 + lrow;
        unsigned p01 = cvtpk(acc[ct][0], acc[ct][1]);
        unsigned p23 = cvtpk(acc[ct][2], acc[ct][3]);
        Cls[(size_t)(lr + 0) * 128 + col] = (u16)p01;
        Cls[(size_t)(lr + 1) * 128 + col] = (u16)(p01 >> 16);
        Cls[(size_t)(lr + 2) * 128 + col] = (u16)p23;
        Cls[(size_t)(lr + 3) * 128 + col] = (u16)(p23 >> 16);
      }
    }
    __syncthreads();
#pragma unroll
    for (int i = 0; i < 4; i++) {
      int c = i * 512 + tid;
      int row = c >> 4, g = c & 15;
      int grow = bm + row;
      if (grow < rows)
        *(uint4*)(Pn + (size_t)grow * 128 + g * 8) =
            *(const uint4*)(Cls + (size_t)row * 128 + g * 8);
    }
    return;
  }
  if (!doRd || !side2) return;
  // ---------- fused readout (conn side, last round): h_new resident in Hls ----------
  bf16x8 ar[4];
#pragma unroll
  for (int ks = 0; ks < 4; ks++)
    ar[ks] = *(const bf16x8*)(Hls + (size_t)(wv * 16 + lrow) * 128 + (((ks * 4 + quad) ^ lrow) * 8));
#pragma unroll
  for (int j = 0; j < 4; j++) {
    int c = j * 512 + tid;
    int row = c >> 4, sl = c & 15;
    gld16(w1r + (size_t)row * 128 + ((sl ^ (row & 15)) * 8), Wls + (size_t)c * 8);
  }
  __syncthreads();  // W1 ready; all Hls reads (ar) drained block-wide
#pragma unroll
  for (int ct = 0; ct < 8; ct++) acc[ct] = {0.f, 0.f, 0.f, 0.f};
#pragma unroll
  for (int ks = 0; ks < 4; ks++) {
#pragma unroll
    for (int ct = 0; ct < 8; ct++) {
      bf16x8 b = *(const bf16x8*)(Wls + (size_t)(ct * 16 + lrow) * 128 + (((4 * ks + quad) ^ lrow) * 8));
      acc[ct] = __builtin_amdgcn_mfma_f32_16x16x32_bf16(ar[ks], b, acc[ct], 0, 0, 0);
    }
  }
  // H1 -> Hls, swizzled (GRU-style write; each wave writes only its own 16 rows)
#pragma unroll
  for (int ct = 0; ct < 8; ct++) {
    int col = ct * 16 + lrow;
    float bv = b1r[col];
    int ggr = 2 * ct + (lrow >> 3);
    int gel = lrow & 7;
    unsigned p01 = cvtpk(fmaxf(acc[ct][0] + bv, 0.f), fmaxf(acc[ct][1] + bv, 0.f));
    unsigned p23 = cvtpk(fmaxf(acc[ct][2] + bv, 0.f), fmaxf(acc[ct][3] + bv, 0.f));
#define H1PTR(R) (Hls + (size_t)(lr0 + (R)) * 128 + ((ggr ^ ((lr0 + (R)) & 15)) * 8) + gel)
    *H1PTR(0) = (u16)p01;
    *H1PTR(1) = (u16)(p01 >> 16);
    *H1PTR(2) = (u16)p23;
    *H1PTR(3) = (u16)(p23 >> 16);
#undef H1PTR
  }
  __syncthreads();  // W1 reads done block-wide
#pragma unroll
  for (int j = 0; j < 2; j++) {  // stage W2 (64x128, 16KB)
    int c = j * 512 + tid;
    int row = c >> 4, sl = c & 15;
    gld16(w2r + (size_t)row * 128 + ((sl ^ (row & 15)) * 8), Wls + (size_t)c * 8);
  }
  __syncthreads();  // W2 ready; H1 visible
  bf16x8 a2[4];
#pragma unroll
  for (int ks = 0; ks < 4; ks++)
    a2[ks] = *(const bf16x8*)(Hls + (size_t)(wv * 16 + lrow) * 128 + (((ks * 4 + quad) ^ lrow) * 8));
  floatx4 acc2[4];
#pragma unroll
  for (int ct = 0; ct < 4; ct++) acc2[ct] = {0.f, 0.f, 0.f, 0.f};
#pragma unroll
  for (int ks = 0; ks < 4; ks++) {
#pragma unroll
    for (int ct = 0; ct < 4; ct++) {
      bf16x8 b = *(const bf16x8*)(Wls + (size_t)(ct * 16 + lrow) * 128 + (((4 * ks + quad) ^ lrow) * 8));
      acc2[ct] = __builtin_amdgcn_mfma_f32_16x16x32_bf16(a2[ks], b, acc2[ct], 0, 0, 0);
    }
  }
  __syncthreads();  // W2 reads done; region0 -> H2/W3
  u16* H2 = (u16*)smem;                    // 128 x 72 bf16 (18432 B)
  float* W3ls = (float*)(smem + 18432);    // 960 f32
  float* b3ls = (float*)(smem + 18432 + 3840);
#pragma unroll
  for (int ct = 0; ct < 4; ct++) {
    int col = ct * 16 + lrow;
    float bv = b2r[col];
#pragma unroll
    for (int reg = 0; reg < 4; reg++)
      H2[(size_t)(lr0 + reg) * 72 + col] = f2bf(fmaxf(acc2[ct][reg] + bv, 0.f));
  }
  for (int l = tid; l < 960; l += 512) W3ls[l] = W3r[l];
  if (tid < 15) b3ls[tid] = b3r[tid];
  __syncthreads();
  // --- parallel logits: 512 threads = 32 row-groups x 16 cols; 16-lane softmax ---
  {
    int col = tid & 15;         // 0..14 valid, 15 idle
    int rb = (tid >> 4) * 4;    // rows 0..127
    float lg[4] = {0.f, 0.f, 0.f, 0.f};
    if (col < 15) {
      float b3v = b3ls[col];
      lg[0] = b3v; lg[1] = b3v; lg[2] = b3v; lg[3] = b3v;
      for (int k8 = 0; k8 < 64; k8 += 8) {
        float w[8];
#pragma unroll
        for (int j = 0; j < 8; j++) w[j] = W3ls[(k8 + j) * 15 + col];
#pragma unroll
        for (int r = 0; r < 4; r++) {
          bf16x8 hv = *(const bf16x8*)(H2 + (size_t)(rb + r) * 72 + k8);
#pragma unroll
          for (int j = 0; j < 8; j++) lg[r] += bf2f((u16)hv[j]) * w[j];
        }
      }
    }
#pragma unroll
    for (int r = 0; r < 4; r++) {
      float v = (col < 15) ? lg[r] : -3.0e38f;
      float m = v;
#pragma unroll
      for (int d = 1; d < 16; d <<= 1) m = fmaxf(m, __shfl_xor(m, d, 16));
      float e = (col < 15) ? __expf(lg[r] - m) : 0.f;
      float s = e;
#pragma unroll
      for (int d = 1; d < 16; d <<= 1) s += __shfl_xor(s, d, 16);
      int gr2 = bm + rb + r;
      if (col < 15 && gr2 < rows) outp[(size_t)gr2 * 15 + col] = e / s;
    }
  }
}

// ---------------- launch ----------------
extern "C" void kernel_launch(void* const* d_in, const int* in_sizes, int n_in,
                              void* d_out, int out_size, void* d_ws, size_t ws_size,
                              hipStream_t stream) {
  const float* feat = (const float*)d_in[0];
  const int* src1 = (const int*)d_in[1];
  const int* dst1 = (const int*)d_in[2];
  const int* src2 = (const int*)d_in[3];
  const int* dst2 = (const int*)d_in[4];
  const float* Wm1 = (const float*)d_in[5];
  const float* bm1 = (const float*)d_in[6];
  const float* Wm2 = (const float*)d_in[7];
  const float* bm2 = (const float*)d_in[8];
  const float* gik = (const float*)d_in[9];
  const float* gir = (const float*)d_in[10];
  const float* gib = (const float*)d_in[11];
  const float* gck = (const float*)d_in[12];
  const float* gcr = (const float*)d_in[13];
  const float* gcb = (const float*)d_in[14];
  const float* Wr1 = (const float*)d_in[15];
  const float* br1 = (const float*)d_in[16];
  const float* Wr2 = (const float*)d_in[17];
  const float* br2 = (const float*)d_in[18];
  const float* Wr3 = (const float*)d_in[19];
  const float* br3 = (const float*)d_in[20];
  float* out = (float*)d_out;

  // ---- workspace layout (u16 units) ----
  u16* w16 = (u16*)d_ws;
  size_t o = 0;
  u16* ip_state = w16 + o;   o += (size_t)N_IP * D;
  u16* conn_state = w16 + o; o += (size_t)N_CONN * D;
  u16* P1a = w16 + o;        o += (size_t)N_IP * D;
  u16* P2a = w16 + o;        o += (size_t)N_CONN * D;
  u16* P1b = w16 + o;        o += (size_t)N_IP * D;
  u16* P2b = w16 + o;        o += (size_t)N_CONN * D;
  u16* gikb = w16 + o;       o += 49152;
  u16* girb = w16 + o;       o += 49152;
  u16* gckb = w16 + o;       o += 49152;
  u16* gcrb = w16 + o;       o += 49152;
  u16* wm1b = w16 + o;       o += 16384;
  u16* wm2b = w16 + o;       o += 16384;
  u16* wm1t = w16 + o;       o += 16384;
  u16* wm2t = w16 + o;       o += 16384;
  u16* wr1b = w16 + o;       o += 16384;
  u16* wr2b = w16 + o;       o += 8192;
  float* csum = (float*)(w16 + o); o += 256;
  int* ip = (int*)(w16 + o);
  int* cnt1 = ip;  ip += N_CONN;   // cnt1, cnt2, gctr contiguous -> ONE memset
  int* cnt2 = ip;  ip += N_IP;
  int* gctr = ip;  ip += 8;
  int* off1 = ip;  ip += N_CONN;
  int* off2 = ip;  ip += N_IP;
  int* cur1 = ip;  ip += N_CONN;
  int* cur2 = ip;  ip += N_IP;
  int* srcs1 = ip; ip += NE + 8;   // +8 pad: unconditional 4-wide prefetch in-bounds
  int* srcs2 = ip; ip += NE + 8;

  const int BT = 256;

  // ---- zero counters (DMA, graph-capture-safe), then ONE merged setup kernel ----
  hipMemsetAsync(cnt1, 0, (size_t)(N_CONN + N_IP + 8) * sizeof(int), stream);
  k_setup<<<N_CONN / 16, BT, 0, stream>>>(  // 6250 blocks
      feat, dst1, dst2, cnt1, cnt2, P2a,
      gik, gir, gck, gcr, Wm1, Wm2, Wr1, Wr2,
      gikb, girb, gckb, gcrb, wm1b, wm2b, wm1t, wm2t, wr1b, wr2b, csum);

  // ---- build CSR: single-kernel alloc + scatter ----
  const int nb1 = (N_CONN + 1023) / 1024, nb2 = (N_IP + 1023) / 1024;
  k_alloc<<<nb1 + nb2, 256, 0, stream>>>(cnt1, off1, cur1, N_CONN, nb1,
                                         cnt2, off2, cur2, N_IP, gctr);
  k_scatter<<<(NE + BT - 1) / BT, BT, 0, stream>>>(src1, dst1, src2, dst2,
                                                   cur1, cur2, srcs1, srcs2);

  const int t128ip = (N_IP + 127) / 128;    // 157
  const int t128cn = (N_CONN + 127) / 128;  // 782

  u16* P1buf[2] = {P1a, P1b};
  u16* P2buf[2] = {P2a, P2b};
  for (int t = 0; t < T_ROUNDS; t++) {
    int cu = t & 1, nx = cu ^ 1;
    int last = (t == T_ROUNDS - 1);
    int grid = last ? t128cn : (t128ip + t128cn);
    int tiles1 = last ? 0 : t128ip;
    k_msggru<<<grid, 512, 0, stream>>>(
        ip_state, wm2b, bm2, P2buf[cu], srcs2, off2, cnt2, gikb, girb, gib,
        wm1t, P1buf[nx], N_IP, tiles1,
        conn_state, wm1b, bm1, P1buf[cu], srcs1, off1, cnt1, gckb, gcrb, gcb,
        wm2t, P2buf[nx], N_CONN, last ? 0 : 1,
        wr1b, br1, wr2b, br2, Wr3, br3, out, last ? 1 : 0,
        feat, csum, (t == 0) ? 1 : 0);
  }
}

// Round 14
// 417.865 us; speedup vs baseline: 1.0523x; 1.0523x over previous
//
#include <hip/hip_runtime.h>
#include <math.h>

#define D 128
#define NF 10
#define N_IP 20000
#define N_CONN 100000
#define NE 200000
#define T_ROUNDS 3

typedef unsigned short u16;
using bf16x8 = __attribute__((ext_vector_type(8))) short;
using floatx4 = __attribute__((ext_vector_type(4))) float;

__device__ inline u16 f2bf(float f) {
  union { float f; unsigned u; } v; v.f = f;
  unsigned u = v.u;
  return (u16)((u + 0x7fffu + ((u >> 16) & 1u)) >> 16);  // RNE
}
__device__ inline float bf2f(u16 h) {
  union { unsigned u; float f; } v; v.u = ((unsigned)h) << 16; return v.f;
}
// HW packed f32->bf16 (RNE, identical to f2bf) — 1 inst per 2 values.
__device__ __forceinline__ unsigned cvtpk(float lo, float hi) {
  unsigned r;
  asm("v_cvt_pk_bf16_f32 %0, %1, %2" : "=v"(r) : "v"(lo), "v"(hi));
  return r;
}

__device__ inline float fsigmoid(float s) { return 1.f / (1.f + __expf(-s)); }
__device__ inline float ftanh(float a) {
  a = fminf(fmaxf(a, -15.f), 15.f);
  float e = __expf(2.f * a);
  return (e - 1.f) / (e + 1.f);
}

// async global->LDS, 16B per lane. LDS dest is wave-linear (base + lane*16B);
// swizzled layouts are realized by pre-swizzling the per-lane GLOBAL address.
__device__ __forceinline__ void gld16(const u16* g, u16* l) {
  __builtin_amdgcn_global_load_lds(
      (const __attribute__((address_space(1))) unsigned int*)g,
      (__attribute__((address_space(3))) unsigned int*)l, 16, 0, 0);
}

// ---------------- merged setup: weights + colsum + edge count + P2 init ----------------
// cnt/gctr pre-zeroed via hipMemsetAsync. Weight prep iterates in SOURCE-linear order
// (reads fully coalesced; 2B writes strided — fire-and-forget). P2 part: one block =
// 16 conn nodes, feat rows LDS-staged via aligned float2 loads.
// Grid: N_CONN/16 = 6250 blocks x 256.
__global__ void k_setup(const float* __restrict__ feat,
                        const int* __restrict__ d1, const int* __restrict__ d2,
                        int* __restrict__ c1, int* __restrict__ c2,
                        u16* __restrict__ P2,
                        const float* __restrict__ gik, const float* __restrict__ gir,
                        const float* __restrict__ gck, const float* __restrict__ gcr,
                        const float* __restrict__ Wm1, const float* __restrict__ Wm2,
                        const float* __restrict__ Wr1, const float* __restrict__ Wr2,
                        u16* __restrict__ gikb, u16* __restrict__ girb,
                        u16* __restrict__ gckb, u16* __restrict__ gcrb,
                        u16* __restrict__ wm1b, u16* __restrict__ wm2b,
                        u16* __restrict__ wm1t, u16* __restrict__ wm2t,
                        u16* __restrict__ wr1b, u16* __restrict__ wr2b,
                        float* __restrict__ csum) {
  __shared__ float featLs[160];  // 16 nodes x 10 features
  const int b = blockIdx.x, t = threadIdx.x;
  const int i = b * 256 + t;
  // stage this block's 16 feat rows (160 contiguous floats, 8B-aligned float2 loads)
  if (t < 80) {
    float2 v = *(const float2*)(feat + (size_t)b * 160 + 2 * t);
    featLs[2 * t] = v.x;
    featLs[2 * t + 1] = v.y;
  }
  // edge degree counting (cnt pre-zeroed by memset)
  if (i < NE) {
    atomicAdd(&c1[d1[i]], 1);
    atomicAdd(&c2[d2[i]], 1);
  }
  // weight prep — SOURCE-linear indexing: consecutive threads read consecutive floats.
  if (i < 196608) {  // 4 GRU mats [128][384] -> [col][k] bf16
    int m = i / 49152, r = i % 49152;  // r == k*384 + col (linear read)
    const float* W = (m == 0) ? gik : (m == 1) ? gir : (m == 2) ? gck : gcr;
    u16* Wb = (m == 0) ? gikb : (m == 1) ? girb : (m == 2) ? gckb : gcrb;
    int k = r / 384, col = r % 384;
    Wb[(size_t)col * 128 + k] = f2bf(W[r]);
  } else if (i < 278528) {  // 5 x 128x128 blocks
    int j = i - 196608;
    int m = j / 16384, r = j % 16384;  // r == k*128 + col (linear within block)
    const float* W; u16* Wb; int k0;
    if (m == 0) { W = Wm1; Wb = wm1b; k0 = 128; }
    else if (m == 1) { W = Wm2; Wb = wm2b; k0 = 128; }
    else if (m == 2) { W = Wm1; Wb = wm1t; k0 = 0; }
    else if (m == 3) { W = Wm2; Wb = wm2t; k0 = 0; }
    else { W = Wr1; Wb = wr1b; k0 = 0; }
    int k = r / 128, col = r % 128;
    Wb[(size_t)col * 128 + k] = f2bf(W[(size_t)k0 * 128 + r]);
  } else if (i < 286720) {  // Wr2 [128][64] -> [col][k]
    int r = i - 278528;  // r == k*64 + col
    int k = r / 64, col = r % 64;
    wr2b[(size_t)col * 128 + k] = f2bf(Wr2[r]);
  } else if (i < 286848) {  // colsum of Wm1_top (ip_state0 == 1)
    int c = i - 286720;
    float s = 0.f;
    for (int k = 0; k < 128; k++) s += Wm1[k * 128 + c];
    csum[c] = s;
  }
  __syncthreads();
  // P2_0 = feat @ Wm2[0:NF,:] for node r = b*16 + (t>>4), col group g = t&15.
  {
    int nl = t >> 4, g = t & 15;
    int r = b * 16 + nl;  // 6250*16 == N_CONN exactly
    float acc[8] = {0.f, 0.f, 0.f, 0.f, 0.f, 0.f, 0.f, 0.f};
#pragma unroll
    for (int k = 0; k < NF; k++) {
      float f = featLs[nl * 10 + k];
      const float* wrow = Wm2 + (size_t)k * 128 + g * 8;
#pragma unroll
      for (int c = 0; c < 8; c++) acc[c] += f * wrow[c];
    }
    u16 v[8];
#pragma unroll
    for (int c = 0; c < 8; c++) v[c] = f2bf(acc[c]);
    *(uint4*)(P2 + (size_t)r * 128 + g * 8) = *(const uint4*)v;
  }
}

// ---------------- single-kernel CSR offset allocation ----------------
__global__ void k_alloc(const int* __restrict__ cnt1, int* __restrict__ off1,
                        int* __restrict__ cur1, int n1, int nb1,
                        const int* __restrict__ cnt2, int* __restrict__ off2,
                        int* __restrict__ cur2, int n2, int* __restrict__ gctr) {
  const int* cnt; int* off; int* cur; int n, b; int* g;
  if ((int)blockIdx.x < nb1) {
    cnt = cnt1; off = off1; cur = cur1; n = n1; b = blockIdx.x; g = gctr;
  } else {
    cnt = cnt2; off = off2; cur = cur2; n = n2; b = blockIdx.x - nb1; g = gctr + 1;
  }
  int t = threadIdx.x;
  int base = b * 1024 + t * 4;
  int vals[4]; int s = 0;
#pragma unroll
  for (int i = 0; i < 4; i++) {
    int j = base + i;
    vals[i] = (j < n) ? cnt[j] : 0;
    s += vals[i];
  }
  int lane = t & 63, wv = t >> 6;
  int x = s;
  for (int d = 1; d < 64; d <<= 1) { int y = __shfl_up(x, d, 64); if (lane >= d) x += y; }
  __shared__ int wsum[4];
  __shared__ int gbase;
  if (lane == 63) wsum[wv] = x;
  __syncthreads();
  int add = 0;
  for (int i = 0; i < wv; i++) add += wsum[i];
  if (t == 0) gbase = atomicAdd(g, wsum[0] + wsum[1] + wsum[2] + wsum[3]);
  __syncthreads();
  int run = gbase + add + x - s;
#pragma unroll
  for (int i = 0; i < 4; i++) {
    int j = base + i;
    if (j < n) { off[j] = run; cur[j] = run; }
    run += vals[i];
  }
}

__global__ void k_scatter(const int* __restrict__ s1, const int* __restrict__ d1,
                          const int* __restrict__ s2, const int* __restrict__ d2,
                          int* __restrict__ cur1, int* __restrict__ cur2,
                          int* __restrict__ o1, int* __restrict__ o2) {
  int e = blockIdx.x * blockDim.x + threadIdx.x;
  if (e >= NE) return;
  int p1 = atomicAdd(&cur1[d1[e]], 1);
  o1[p1] = s1[e];
  int p2 = atomicAdd(&cur2[d2[e]], 1);
  o2[p2] = s2[e];
}

// ---------------- fused message+GRU+{nextP | readout}: 512 threads, 128 rows/block ----------------
// an0 (round 0): states synthesized analytically — ip: ah/h_old = 1.0 (no H staging,
// no ip_state read); conn: Hls built from feat in-LDS; conn gather is the closed form
// t = relu(bf2f(f2bf(csum)) + q) added n times (bit-exact vs gathering identical P1 rows).
// (Round-13's srcs prefetch REVERTED: its 16 live VGPRs across the Q-GEMM caused
// scratch spill — WRITE +28MB, dur +17µs. This is the verified round-11 body.)
__global__ __launch_bounds__(512, 4) void k_msggru(
    u16* __restrict__ st1, const u16* __restrict__ wq1, const float* __restrict__ qb1,
    const u16* __restrict__ P1g, const int* __restrict__ srcs1g,
    const int* __restrict__ off1g, const int* __restrict__ cnt1g,
    const u16* __restrict__ wx1, const u16* __restrict__ wh1, const float* __restrict__ gb1,
    const u16* __restrict__ wp1, u16* __restrict__ Pn1, int r1, int tiles1,
    u16* __restrict__ st2, const u16* __restrict__ wq2, const float* __restrict__ qb2,
    const u16* __restrict__ P2g, const int* __restrict__ srcs2g,
    const int* __restrict__ off2g, const int* __restrict__ cnt2g,
    const u16* __restrict__ wx2, const u16* __restrict__ wh2, const float* __restrict__ gb2,
    const u16* __restrict__ wp2, u16* __restrict__ Pn2, int r2, int doP,
    const u16* __restrict__ w1r, const float* __restrict__ b1r,
    const u16* __restrict__ w2r, const float* __restrict__ b2r,
    const float* __restrict__ W3r, const float* __restrict__ b3r,
    float* __restrict__ outp, int doRd,
    const float* __restrict__ featp, const float* __restrict__ csumP, int an0) {
  __shared__ __align__(16) char smem[65536];
  u16* Wls = (u16*)smem;                   // staged weight matrix (up to 32KB)
  u16* Qb = (u16*)smem;                    // 128x128 bf16 (32KB); Xb overlays swizzled
  u16* bufA = (u16*)smem;                  // GRU x-gates chunk (12KB)
  u16* bufB = (u16*)(smem + 12288);        // GRU h-gates chunk (12KB)
  u16* Hls = (u16*)(smem + 32768);         // 128x128 bf16 swizzled (32KB)
  u16* H; const u16* Wqb; const float* qbias; const u16* P;
  const int* srcs; const int* off; const int* cnt;
  const u16* Wxb; const u16* Whb; const float* gbias;
  const u16* Wpt; u16* Pn; int rows, bm;
  const bool side2 = (int)blockIdx.x >= tiles1;
  if (!side2) {
    H = st1; Wqb = wq1; qbias = qb1; P = P1g; srcs = srcs1g; off = off1g; cnt = cnt1g;
    Wxb = wx1; Whb = wh1; gbias = gb1; Wpt = wp1; Pn = Pn1; rows = r1; bm = blockIdx.x * 128;
  } else {
    H = st2; Wqb = wq2; qbias = qb2; P = P2g; srcs = srcs2g; off = off2g; cnt = cnt2g;
    Wxb = wx2; Whb = wh2; gbias = gb2; Wpt = wp2; Pn = Pn2; rows = r2;
    bm = (blockIdx.x - tiles1) * 128;
  }
  const int tid = threadIdx.x, wv = tid >> 6, lane = tid & 63;
  const int lrow = lane & 15, quad = lane >> 4;
  const bool anIp = an0 && !side2;    // analytic all-ones state
  const bool anConn = an0 && side2;   // analytic [feat|0] state + closed-form gather
  // --- phase A: issue FULL Wq (2048 chunks) + H staging ---
#pragma unroll
  for (int j = 0; j < 4; j++) {
    int c = j * 512 + tid;
    int row = c >> 4, sl = c & 15;
    gld16(Wqb + (size_t)row * 128 + ((sl ^ (row & 15)) * 8), Wls + (size_t)c * 8);
  }
  if (!an0) {
#pragma unroll
    for (int i = 0; i < 4; i++) {
      int c = i * 512 + tid;
      int row = c >> 4, sl = c & 15;
      gld16(H + (size_t)(bm + row) * 128 + ((sl ^ (row & 15)) * 8), Hls + (size_t)c * 8);
    }
  } else if (anConn) {
    // synthesize conn_state0 = [feat|0] directly into Hls (swizzled), same f2bf values
#pragma unroll
    for (int i = 0; i < 4; i++) {
      int c = i * 512 + tid;
      int row = c >> 4, sl = c & 15;
      int grow = bm + row;
      u16 v[8];
#pragma unroll
      for (int k = 0; k < 8; k++) {
        int col = sl * 8 + k;
        v[k] = (grow < rows && col < NF) ? f2bf(featp[(size_t)grow * NF + col]) : (u16)0;
      }
      *(uint4*)(Hls + (size_t)row * 128 + ((sl ^ (row & 15)) * 8)) = *(const uint4*)v;
    }
  }
  // off/cnt for this thread's 4 gather tasks -> registers (16-lane broadcast loads)
  int oArr[4], nArr[4];
#pragma unroll
  for (int it = 0; it < 4; it++) {
    int nl = (it * 512 + tid) >> 4;
    int node = bm + nl;
    oArr[it] = (node < rows) ? off[node] : 0;
    nArr[it] = (node < rows) ? cnt[node] : 0;
  }
  __syncthreads();  // Wq + Hls ready
  // state A-frags (serve Q-GEMM and GRU h-GEMM); wave wv owns rows [wv*16, wv*16+16)
  bf16x8 ah[4];
  if (anIp) {
    bf16x8 ones;
#pragma unroll
    for (int k = 0; k < 8; k++) ones[k] = (short)0x3F80;  // bf16(1.0)
#pragma unroll
    for (int ks = 0; ks < 4; ks++) ah[ks] = ones;
  } else {
#pragma unroll
    for (int ks = 0; ks < 4; ks++)
      ah[ks] = *(const bf16x8*)(Hls + (size_t)(wv * 16 + lrow) * 128 + (((ks * 4 + quad) ^ lrow) * 8));
  }
  // --- Q-GEMM: full 128 cols in one pass ---
  floatx4 acc[8];
#pragma unroll
  for (int ct = 0; ct < 8; ct++) acc[ct] = {0.f, 0.f, 0.f, 0.f};
#pragma unroll
  for (int ks = 0; ks < 4; ks++) {
#pragma unroll
    for (int ct = 0; ct < 8; ct++) {
      bf16x8 b = *(const bf16x8*)(Wls + (size_t)(ct * 16 + lrow) * 128 + (((4 * ks + quad) ^ lrow) * 8));
      acc[ct] = __builtin_amdgcn_mfma_f32_16x16x32_bf16(ah[ks], b, acc[ct], 0, 0, 0);
    }
  }
  __syncthreads();  // Wq reads done; region0 becomes Qb
  // --- write Q (+bias) as bf16 via cvt_pk, plain [row][col] ---
  {
    const int lr = wv * 16 + quad * 4;
#pragma unroll
    for (int ct = 0; ct < 8; ct++) {
      int col = ct * 16 + lrow;
      float bv = qbias[col];
      unsigned p01 = cvtpk(acc[ct][0] + bv, acc[ct][1] + bv);
      unsigned p23 = cvtpk(acc[ct][2] + bv, acc[ct][3] + bv);
      Qb[(size_t)(lr + 0) * 128 + col] = (u16)p01;
      Qb[(size_t)(lr + 1) * 128 + col] = (u16)(p01 >> 16);
      Qb[(size_t)(lr + 2) * 128 + col] = (u16)p23;
      Qb[(size_t)(lr + 3) * 128 + col] = (u16)(p23 >> 16);
    }
  }
  __syncthreads();
  // --- gather-mean: X[node] = mean_e relu(P[src_e] + Q[node]) -> Xb (=Qb, swizzled)
#pragma unroll
  for (int it = 0; it < 4; it++) {
    int task = it * 512 + tid;
    int nl = task >> 4, g = task & 15;
    int node = bm + nl;
    if (node >= rows) continue;
    int c8 = g << 3;
    float q[8];
    {
      uint4 qv = *(const uint4*)(Qb + (size_t)nl * 128 + c8);
      unsigned qq[4] = {qv.x, qv.y, qv.z, qv.w};
#pragma unroll
      for (int k = 0; k < 4; k++) {
        q[2 * k] = __uint_as_float(qq[k] << 16);
        q[2 * k + 1] = __uint_as_float(qq[k] & 0xffff0000u);
      }
    }
    float acg[8] = {0.f, 0.f, 0.f, 0.f, 0.f, 0.f, 0.f, 0.f};
    int n = nArr[it];
    if (anConn) {
      // P1 round-0 rows are ALL IDENTICAL (= f2bf(csum)); mean over n copies ==
      // t added n times then * 1/max(n,1) — exact FP op order of the gather loop.
      float t[8];
#pragma unroll
      for (int k = 0; k < 8; k++)
        t[k] = fmaxf(bf2f(f2bf(csumP[c8 + k])) + q[k], 0.f);
      for (int i = 0; i < n; i++) {
#pragma unroll
        for (int k = 0; k < 8; k++) acg[k] += t[k];
      }
    } else {
      int o = oArr[it];
      for (int i = 0; i < n; i += 4) {
        int rem = n - i;
        int s0 = srcs[o + i];
        int s1 = srcs[o + i + (rem > 1 ? 1 : 0)];
        int s2 = srcs[o + i + (rem > 2 ? 2 : 0)];
        int s3 = srcs[o + i + (rem > 3 ? 3 : 0)];
        uint4 v0 = *(const uint4*)(P + (size_t)s0 * 128 + c8);
        uint4 v1 = *(const uint4*)(P + (size_t)s1 * 128 + c8);
        uint4 v2 = *(const uint4*)(P + (size_t)s2 * 128 + c8);
        uint4 v3 = *(const uint4*)(P + (size_t)s3 * 128 + c8);
        unsigned w[16] = {v0.x, v0.y, v0.z, v0.w, v1.x, v1.y, v1.z, v1.w,
                          v2.x, v2.y, v2.z, v2.w, v3.x, v3.y, v3.z, v3.w};
#pragma unroll
        for (int e = 0; e < 4; e++) {
          bool val = (e == 0) || (rem > e);
#pragma unroll
          for (int k = 0; k < 4; k++) {
            unsigned ww = w[e * 4 + k];
            float lo = __uint_as_float(ww << 16);
            float hi = __uint_as_float(ww & 0xffff0000u);
            float t0 = fmaxf(lo + q[2 * k], 0.f);
            float t1 = fmaxf(hi + q[2 * k + 1], 0.f);
            if (val) { acg[2 * k] += t0; acg[2 * k + 1] += t1; }
          }
        }
      }
    }
    float inv = 1.f / fmaxf((float)n, 1.f);
    uint4 ov;
    ov.x = cvtpk(acg[0] * inv, acg[1] * inv);
    ov.y = cvtpk(acg[2] * inv, acg[3] * inv);
    ov.z = cvtpk(acg[4] * inv, acg[5] * inv);
    ov.w = cvtpk(acg[6] * inv, acg[7] * inv);
    *(uint4*)(Qb + (size_t)nl * 128 + ((g ^ (nl & 15)) * 8)) = ov;  // Xb overlay
  }
  __syncthreads();
  // --- x A-frags from Xb (= Qb region, swizzled) ---
  bf16x8 ax[4];
#pragma unroll
  for (int ks = 0; ks < 4; ks++)
    ax[ks] = *(const bf16x8*)(Qb + (size_t)(wv * 16 + lrow) * 128 + (((ks * 4 + quad) ^ lrow) * 8));
  const int lr0 = wv * 16 + quad * 4;
  __syncthreads();  // all Xb/Qb reads done; region0 free for GRU staging
  // --- GRU chunk loop: x/h ping-pong via global_load_lds (768 16B-chunks per buf) ---
#pragma unroll
  for (int j = 0; j < 2; j++) {  // stage x(0) -> bufA
    int c = j * 512 + tid;
    if (c < 768) {
      int gate = c >> 8, colw = (c >> 4) & 15, sl = c & 15;
      gld16(Wxb + (size_t)(gate * 128 + 0 * 16 + colw) * 128 + ((sl ^ colw) * 8),
            bufA + (size_t)c * 8);
    }
  }
  for (int ch = 0; ch < 8; ch++) {
    __syncthreads();  // bufA=x(ch) ready; prev bufB reads done
#pragma unroll
    for (int j = 0; j < 2; j++) {  // stage h(ch) -> bufB (overlaps MFMA-x)
      int c = j * 512 + tid;
      if (c < 768) {
        int gate = c >> 8, colw = (c >> 4) & 15, sl = c & 15;
        gld16(Whb + (size_t)(gate * 128 + ch * 16 + colw) * 128 + ((sl ^ colw) * 8),
              bufB + (size_t)c * 8);
      }
    }
    floatx4 gacc[3][2];
#pragma unroll
    for (int g = 0; g < 3; g++) {
      gacc[g][0] = {0.f, 0.f, 0.f, 0.f};
      gacc[g][1] = {0.f, 0.f, 0.f, 0.f};
    }
#pragma unroll
    for (int ks = 0; ks < 4; ks++) {
      int posu = ((4 * ks + quad) ^ lrow) * 8;
#pragma unroll
      for (int g = 0; g < 3; g++) {
        bf16x8 bx = *(const bf16x8*)(bufA + (size_t)(g * 16 + lrow) * 128 + posu);
        gacc[g][0] = __builtin_amdgcn_mfma_f32_16x16x32_bf16(ax[ks], bx, gacc[g][0], 0, 0, 0);
      }
    }
    __syncthreads();  // bufB=h(ch) ready; bufA reads done
    if (ch < 7) {
#pragma unroll
      for (int j = 0; j < 2; j++) {  // stage x(ch+1) -> bufA (overlaps MFMA-h + epilogue)
        int c = j * 512 + tid;
        if (c < 768) {
          int gate = c >> 8, colw = (c >> 4) & 15, sl = c & 15;
          gld16(Wxb + (size_t)(gate * 128 + (ch + 1) * 16 + colw) * 128 + ((sl ^ colw) * 8),
                bufA + (size_t)c * 8);
        }
      }
    }
#pragma unroll
    for (int ks = 0; ks < 4; ks++) {
      int posu = ((4 * ks + quad) ^ lrow) * 8;
#pragma unroll
      for (int g = 0; g < 3; g++) {
        bf16x8 bh = *(const bf16x8*)(bufB + (size_t)(g * 16 + lrow) * 128 + posu);
        gacc[g][1] = __builtin_amdgcn_mfma_f32_16x16x32_bf16(ah[ks], bh, gacc[g][1], 0, 0, 0);
      }
    }
    int hcol = ch * 16 + lrow;
    float bxz = gbias[hcol];
    float bxr = gbias[128 + hcol];
    float bxh = gbias[256 + hcol];
    float bhz = gbias[384 + hcol];
    float bhr = gbias[384 + 128 + hcol];
    float bhh = gbias[384 + 256 + hcol];
    int ggr = 2 * ch + (lrow >> 3);
    int gel = lrow & 7;
    float hn[4];
#pragma unroll
    for (int reg = 0; reg < 4; reg++) {
      int lr = lr0 + reg;
      float xz = gacc[0][0][reg] + bxz;
      float xr = gacc[1][0][reg] + bxr;
      float xh = gacc[2][0][reg] + bxh;
      float hz = gacc[0][1][reg] + bhz;
      float hr = gacc[1][1][reg] + bhr;
      float hh = gacc[2][1][reg] + bhh;
      float z = fsigmoid(xz + hz);
      float rr = fsigmoid(xr + hr);
      float hc = ftanh(xh + rr * hh);
      float hold;
      if (anIp) {
        hold = 1.0f;  // == bf2f(0x3F80)
      } else {
        const u16* hp = Hls + (size_t)lr * 128 + ((ggr ^ (lr & 15)) * 8) + gel;
        hold = bf2f(*hp);
      }
      hn[reg] = z * hold + (1.f - z) * hc;
    }
    unsigned q01 = cvtpk(hn[0], hn[1]);
    unsigned q23 = cvtpk(hn[2], hn[3]);
#define HPTR(R) (Hls + (size_t)(lr0 + (R)) * 128 + ((ggr ^ ((lr0 + (R)) & 15)) * 8) + gel)
    *HPTR(0) = (u16)q01;
    *HPTR(1) = (u16)(q01 >> 16);
    *HPTR(2) = (u16)q23;
    *HPTR(3) = (u16)(q23 >> 16);
#undef HPTR
  }
  __syncthreads();  // Hls updated block-wide; bufA/bufB reads done
  // --- coalesced state write-out (2048 chunks); DEAD in the readout round ---
  if (!doRd) {
#pragma unroll
    for (int i = 0; i < 4; i++) {
      int c = i * 512 + tid;
      int row = c >> 4, g = c & 15;
      int grow = bm + row;
      if (grow < rows)
        *(uint4*)(H + (size_t)grow * 128 + g * 8) =
            *(const uint4*)(Hls + (size_t)row * 128 + ((g ^ (row & 15)) * 8));
    }
  }
  if (doP) {
    // --- fused next-round P: Pn = h_new @ Wm_top, Wp staged FULL in one phase ---
    bf16x8 ah2[4];
#pragma unroll
    for (int ks = 0; ks < 4; ks++)
      ah2[ks] = *(const bf16x8*)(Hls + (size_t)(wv * 16 + lrow) * 128 + (((ks * 4 + quad) ^ lrow) * 8));
#pragma unroll
    for (int j = 0; j < 4; j++) {  // full 32KB Wp into region0 (bufA/B dead)
      int c = j * 512 + tid;
      int row = c >> 4, sl = c & 15;
      gld16(Wpt + (size_t)row * 128 + ((sl ^ (row & 15)) * 8), Wls + (size_t)c * 8);
    }
    __syncthreads();  // Wp ready; all Hls reads (writeout + ah2) done block-wide
#pragma unroll
    for (int ct = 0; ct < 8; ct++) acc[ct] = {0.f, 0.f, 0.f, 0.f};
#pragma unroll
    for (int ks = 0; ks < 4; ks++) {
#pragma unroll
      for (int ct = 0; ct < 8; ct++) {
        bf16x8 b = *(const bf16x8*)(Wls + (size_t)(ct * 16 + lrow) * 128 + (((4 * ks + quad) ^ lrow) * 8));
        acc[ct] = __builtin_amdgcn_mfma_f32_16x16x32_bf16(ah2[ks], b, acc[ct], 0, 0, 0);
      }
    }
    // Cls bounce over dead Hls
    u16* Cls = Hls;
    {
      const int lr = wv * 16 + quad * 4;
#pragma unroll
      for (int ct = 0; ct < 8; ct++) {
        int col = ct * 16 + lrow;
        unsigned p01 = cvtpk(acc[ct][0], acc[ct][1]);
        unsigned p23 = cvtpk(acc[ct][2], acc[ct][3]);
        Cls[(size_t)(lr + 0) * 128 + col] = (u16)p01;
        Cls[(size_t)(lr + 1) * 128 + col] = (u16)(p01 >> 16);
        Cls[(size_t)(lr + 2) * 128 + col] = (u16)p23;
        Cls[(size_t)(lr + 3) * 128 + col] = (u16)(p23 >> 16);
      }
    }
    __syncthreads();
#pragma unroll
    for (int i = 0; i < 4; i++) {
      int c = i * 512 + tid;
      int row = c >> 4, g = c & 15;
      int grow = bm + row;
      if (grow < rows)
        *(uint4*)(Pn + (size_t)grow * 128 + g * 8) =
            *(const uint4*)(Cls + (size_t)row * 128 + g * 8);
    }
    return;
  }
  if (!doRd || !side2) return;
  // ---------- fused readout (conn side, last round): h_new resident in Hls ----------
  bf16x8 ar[4];
#pragma unroll
  for (int ks = 0; ks < 4; ks++)
    ar[ks] = *(const bf16x8*)(Hls + (size_t)(wv * 16 + lrow) * 128 + (((ks * 4 + quad) ^ lrow) * 8));
#pragma unroll
  for (int j = 0; j < 4; j++) {
    int c = j * 512 + tid;
    int row = c >> 4, sl = c & 15;
    gld16(w1r + (size_t)row * 128 + ((sl ^ (row & 15)) * 8), Wls + (size_t)c * 8);
  }
  __syncthreads();  // W1 ready; all Hls reads (ar) drained block-wide
#pragma unroll
  for (int ct = 0; ct < 8; ct++) acc[ct] = {0.f, 0.f, 0.f, 0.f};
#pragma unroll
  for (int ks = 0; ks < 4; ks++) {
#pragma unroll
    for (int ct = 0; ct < 8; ct++) {
      bf16x8 b = *(const bf16x8*)(Wls + (size_t)(ct * 16 + lrow) * 128 + (((4 * ks + quad) ^ lrow) * 8));
      acc[ct] = __builtin_amdgcn_mfma_f32_16x16x32_bf16(ar[ks], b, acc[ct], 0, 0, 0);
    }
  }
  // H1 -> Hls, swizzled (GRU-style write; each wave writes only its own 16 rows)
#pragma unroll
  for (int ct = 0; ct < 8; ct++) {
    int col = ct * 16 + lrow;
    float bv = b1r[col];
    int ggr = 2 * ct + (lrow >> 3);
    int gel = lrow & 7;
    unsigned p01 = cvtpk(fmaxf(acc[ct][0] + bv, 0.f), fmaxf(acc[ct][1] + bv, 0.f));
    unsigned p23 = cvtpk(fmaxf(acc[ct][2] + bv, 0.f), fmaxf(acc[ct][3] + bv, 0.f));
#define H1PTR(R) (Hls + (size_t)(lr0 + (R)) * 128 + ((ggr ^ ((lr0 + (R)) & 15)) * 8) + gel)
    *H1PTR(0) = (u16)p01;
    *H1PTR(1) = (u16)(p01 >> 16);
    *H1PTR(2) = (u16)p23;
    *H1PTR(3) = (u16)(p23 >> 16);
#undef H1PTR
  }
  __syncthreads();  // W1 reads done block-wide
#pragma unroll
  for (int j = 0; j < 2; j++) {  // stage W2 (64x128, 16KB)
    int c = j * 512 + tid;
    int row = c >> 4, sl = c & 15;
    gld16(w2r + (size_t)row * 128 + ((sl ^ (row & 15)) * 8), Wls + (size_t)c * 8);
  }
  __syncthreads();  // W2 ready; H1 visible
  bf16x8 a2[4];
#pragma unroll
  for (int ks = 0; ks < 4; ks++)
    a2[ks] = *(const bf16x8*)(Hls + (size_t)(wv * 16 + lrow) * 128 + (((ks * 4 + quad) ^ lrow) * 8));
  floatx4 acc2[4];
#pragma unroll
  for (int ct = 0; ct < 4; ct++) acc2[ct] = {0.f, 0.f, 0.f, 0.f};
#pragma unroll
  for (int ks = 0; ks < 4; ks++) {
#pragma unroll
    for (int ct = 0; ct < 4; ct++) {
      bf16x8 b = *(const bf16x8*)(Wls + (size_t)(ct * 16 + lrow) * 128 + (((4 * ks + quad) ^ lrow) * 8));
      acc2[ct] = __builtin_amdgcn_mfma_f32_16x16x32_bf16(a2[ks], b, acc2[ct], 0, 0, 0);
    }
  }
  __syncthreads();  // W2 reads done; region0 -> H2/W3
  u16* H2 = (u16*)smem;                    // 128 x 72 bf16 (18432 B)
  float* W3ls = (float*)(smem + 18432);    // 960 f32
  float* b3ls = (float*)(smem + 18432 + 3840);
#pragma unroll
  for (int ct = 0; ct < 4; ct++) {
    int col = ct * 16 + lrow;
    float bv = b2r[col];
#pragma unroll
    for (int reg = 0; reg < 4; reg++)
      H2[(size_t)(lr0 + reg) * 72 + col] = f2bf(fmaxf(acc2[ct][reg] + bv, 0.f));
  }
  for (int l = tid; l < 960; l += 512) W3ls[l] = W3r[l];
  if (tid < 15) b3ls[tid] = b3r[tid];
  __syncthreads();
  // --- parallel logits: 512 threads = 32 row-groups x 16 cols; 16-lane softmax ---
  {
    int col = tid & 15;         // 0..14 valid, 15 idle
    int rb = (tid >> 4) * 4;    // rows 0..127
    float lg[4] = {0.f, 0.f, 0.f, 0.f};
    if (col < 15) {
      float b3v = b3ls[col];
      lg[0] = b3v; lg[1] = b3v; lg[2] = b3v; lg[3] = b3v;
      for (int k8 = 0; k8 < 64; k8 += 8) {
        float w[8];
#pragma unroll
        for (int j = 0; j < 8; j++) w[j] = W3ls[(k8 + j) * 15 + col];
#pragma unroll
        for (int r = 0; r < 4; r++) {
          bf16x8 hv = *(const bf16x8*)(H2 + (size_t)(rb + r) * 72 + k8);
#pragma unroll
          for (int j = 0; j < 8; j++) lg[r] += bf2f((u16)hv[j]) * w[j];
        }
      }
    }
#pragma unroll
    for (int r = 0; r < 4; r++) {
      float v = (col < 15) ? lg[r] : -3.0e38f;
      float m = v;
#pragma unroll
      for (int d = 1; d < 16; d <<= 1) m = fmaxf(m, __shfl_xor(m, d, 16));
      float e = (col < 15) ? __expf(lg[r] - m) : 0.f;
      float s = e;
#pragma unroll
      for (int d = 1; d < 16; d <<= 1) s += __shfl_xor(s, d, 16);
      int gr2 = bm + rb + r;
      if (col < 15 && gr2 < rows) outp[(size_t)gr2 * 15 + col] = e / s;
    }
  }
}

// ---------------- launch ----------------
extern "C" void kernel_launch(void* const* d_in, const int* in_sizes, int n_in,
                              void* d_out, int out_size, void* d_ws, size_t ws_size,
                              hipStream_t stream) {
  const float* feat = (const float*)d_in[0];
  const int* src1 = (const int*)d_in[1];
  const int* dst1 = (const int*)d_in[2];
  const int* src2 = (const int*)d_in[3];
  const int* dst2 = (const int*)d_in[4];
  const float* Wm1 = (const float*)d_in[5];
  const float* bm1 = (const float*)d_in[6];
  const float* Wm2 = (const float*)d_in[7];
  const float* bm2 = (const float*)d_in[8];
  const float* gik = (const float*)d_in[9];
  const float* gir = (const float*)d_in[10];
  const float* gib = (const float*)d_in[11];
  const float* gck = (const float*)d_in[12];
  const float* gcr = (const float*)d_in[13];
  const float* gcb = (const float*)d_in[14];
  const float* Wr1 = (const float*)d_in[15];
  const float* br1 = (const float*)d_in[16];
  const float* Wr2 = (const float*)d_in[17];
  const float* br2 = (const float*)d_in[18];
  const float* Wr3 = (const float*)d_in[19];
  const float* br3 = (const float*)d_in[20];
  float* out = (float*)d_out;

  // ---- workspace layout (u16 units) ----
  u16* w16 = (u16*)d_ws;
  size_t o = 0;
  u16* ip_state = w16 + o;   o += (size_t)N_IP * D;
  u16* conn_state = w16 + o; o += (size_t)N_CONN * D;
  u16* P1a = w16 + o;        o += (size_t)N_IP * D;
  u16* P2a = w16 + o;        o += (size_t)N_CONN * D;
  u16* P1b = w16 + o;        o += (size_t)N_IP * D;
  u16* P2b = w16 + o;        o += (size_t)N_CONN * D;
  u16* gikb = w16 + o;       o += 49152;
  u16* girb = w16 + o;       o += 49152;
  u16* gckb = w16 + o;       o += 49152;
  u16* gcrb = w16 + o;       o += 49152;
  u16* wm1b = w16 + o;       o += 16384;
  u16* wm2b = w16 + o;       o += 16384;
  u16* wm1t = w16 + o;       o += 16384;
  u16* wm2t = w16 + o;       o += 16384;
  u16* wr1b = w16 + o;       o += 16384;
  u16* wr2b = w16 + o;       o += 8192;
  float* csum = (float*)(w16 + o); o += 256;
  int* ip = (int*)(w16 + o);
  int* cnt1 = ip;  ip += N_CONN;   // cnt1, cnt2, gctr contiguous -> ONE memset
  int* cnt2 = ip;  ip += N_IP;
  int* gctr = ip;  ip += 8;
  int* off1 = ip;  ip += N_CONN;
  int* off2 = ip;  ip += N_IP;
  int* cur1 = ip;  ip += N_CONN;
  int* cur2 = ip;  ip += N_IP;
  int* srcs1 = ip; ip += NE;
  int* srcs2 = ip; ip += NE;

  const int BT = 256;

  // ---- zero counters (DMA, graph-capture-safe), then ONE merged setup kernel ----
  hipMemsetAsync(cnt1, 0, (size_t)(N_CONN + N_IP + 8) * sizeof(int), stream);
  k_setup<<<N_CONN / 16, BT, 0, stream>>>(  // 6250 blocks
      feat, dst1, dst2, cnt1, cnt2, P2a,
      gik, gir, gck, gcr, Wm1, Wm2, Wr1, Wr2,
      gikb, girb, gckb, gcrb, wm1b, wm2b, wm1t, wm2t, wr1b, wr2b, csum);

  // ---- build CSR: single-kernel alloc + scatter ----
  const int nb1 = (N_CONN + 1023) / 1024, nb2 = (N_IP + 1023) / 1024;
  k_alloc<<<nb1 + nb2, 256, 0, stream>>>(cnt1, off1, cur1, N_CONN, nb1,
                                         cnt2, off2, cur2, N_IP, gctr);
  k_scatter<<<(NE + BT - 1) / BT, BT, 0, stream>>>(src1, dst1, src2, dst2,
                                                   cur1, cur2, srcs1, srcs2);

  const int t128ip = (N_IP + 127) / 128;    // 157
  const int t128cn = (N_CONN + 127) / 128;  // 782

  u16* P1buf[2] = {P1a, P1b};
  u16* P2buf[2] = {P2a, P2b};
  for (int t = 0; t < T_ROUNDS; t++) {
    int cu = t & 1, nx = cu ^ 1;
    int last = (t == T_ROUNDS - 1);
    int grid = last ? t128cn : (t128ip + t128cn);
    int tiles1 = last ? 0 : t128ip;
    k_msggru<<<grid, 512, 0, stream>>>(
        ip_state, wm2b, bm2, P2buf[cu], srcs2, off2, cnt2, gikb, girb, gib,
        wm1t, P1buf[nx], N_IP, tiles1,
        conn_state, wm1b, bm1, P1buf[cu], srcs1, off1, cnt1, gckb, gcrb, gcb,
        wm2t, P2buf[nx], N_CONN, last ? 0 : 1,
        wr1b, br1, wr2b, br2, Wr3, br3, out, last ? 1 : 0,
        feat, csum, (t == 0) ? 1 : 0);
  }
}